// Round 2
// baseline (598.787 us; speedup 1.0000x reference)
//
#include <hip/hip_runtime.h>

typedef float v4f __attribute__((ext_vector_type(4)));

#define N_NODES 50000
#define N_ROWS  800000
#define C 128
#define NPAD 50176          // N_NODES rounded up to 196*256
#define NBLK 196            // scan blocks

// W1f = W1[0:128,:] + W1[128:256,:]  (concat([g,g]) @ W1 == g @ W1f)
__global__ __launch_bounds__(256) void prep_w1f(const float* __restrict__ W1,
                                                float* __restrict__ W1f) {
    int i = blockIdx.x * 256 + threadIdx.x;
    if (i < C * C) W1f[i] = W1[i] + W1[C * C + i];
}

// Per-node fused MLP: z = relu(x @ W1f + b1) @ W2 + b2
// 64-row x 128-col tile per 256-thread block; 4x8 register blocking.
__global__ __launch_bounds__(256) void node_kernel(
    const float* __restrict__ x, const float* __restrict__ W1f,
    const float* __restrict__ b1, const float* __restrict__ W2,
    const float* __restrict__ b2, float* __restrict__ z)
{
    __shared__ float smem[64 * 132];
    const int tid = threadIdx.x;
    const int cg  = tid & 15;
    const int rg  = tid >> 4;
    const int c0  = cg * 8;
    const int node0 = blockIdx.x * 64;

    {
        int r  = tid >> 5;
        int c4 = (tid & 31) * 4;
        #pragma unroll
        for (int it = 0; it < 8; ++it, r += 8) {
            int gr = node0 + r;
            if (gr >= N_NODES) gr = N_NODES - 1;
            v4f v = *reinterpret_cast<const v4f*>(&x[(long)gr * C + c4]);
            *reinterpret_cast<v4f*>(&smem[r * 132 + c4]) = v;
        }
    }
    __syncthreads();

    float acc[4][8];
    #pragma unroll
    for (int m = 0; m < 4; ++m)
        #pragma unroll
        for (int j = 0; j < 8; ++j) acc[m][j] = 0.f;

    #pragma unroll 4
    for (int k = 0; k < C; ++k) {
        v4f w0 = *reinterpret_cast<const v4f*>(&W1f[k * C + c0]);
        v4f w1 = *reinterpret_cast<const v4f*>(&W1f[k * C + c0 + 4]);
        #pragma unroll
        for (int m = 0; m < 4; ++m) {
            float xv = smem[(rg + 16 * m) * 132 + k];
            acc[m][0] += xv * w0.x; acc[m][1] += xv * w0.y;
            acc[m][2] += xv * w0.z; acc[m][3] += xv * w0.w;
            acc[m][4] += xv * w1.x; acc[m][5] += xv * w1.y;
            acc[m][6] += xv * w1.z; acc[m][7] += xv * w1.w;
        }
    }

    float bb[8];
    #pragma unroll
    for (int j = 0; j < 8; ++j) bb[j] = b1[c0 + j];

    __syncthreads();
    #pragma unroll
    for (int m = 0; m < 4; ++m) {
        int r = rg + 16 * m;
        v4f h0, h1;
        h0.x = acc[m][0] + bb[0]; h0.y = acc[m][1] + bb[1];
        h0.z = acc[m][2] + bb[2]; h0.w = acc[m][3] + bb[3];
        h1.x = acc[m][4] + bb[4]; h1.y = acc[m][5] + bb[5];
        h1.z = acc[m][6] + bb[6]; h1.w = acc[m][7] + bb[7];
        h0.x = h0.x > 0.f ? h0.x : 0.f; h0.y = h0.y > 0.f ? h0.y : 0.f;
        h0.z = h0.z > 0.f ? h0.z : 0.f; h0.w = h0.w > 0.f ? h0.w : 0.f;
        h1.x = h1.x > 0.f ? h1.x : 0.f; h1.y = h1.y > 0.f ? h1.y : 0.f;
        h1.z = h1.z > 0.f ? h1.z : 0.f; h1.w = h1.w > 0.f ? h1.w : 0.f;
        *reinterpret_cast<v4f*>(&smem[r * 132 + c0])     = h0;
        *reinterpret_cast<v4f*>(&smem[r * 132 + c0 + 4]) = h1;
    }
    __syncthreads();

    #pragma unroll
    for (int m = 0; m < 4; ++m)
        #pragma unroll
        for (int j = 0; j < 8; ++j) acc[m][j] = 0.f;

    #pragma unroll 4
    for (int k = 0; k < C; ++k) {
        v4f w0 = *reinterpret_cast<const v4f*>(&W2[k * C + c0]);
        v4f w1 = *reinterpret_cast<const v4f*>(&W2[k * C + c0 + 4]);
        #pragma unroll
        for (int m = 0; m < 4; ++m) {
            float hv = smem[(rg + 16 * m) * 132 + k];
            acc[m][0] += hv * w0.x; acc[m][1] += hv * w0.y;
            acc[m][2] += hv * w0.z; acc[m][3] += hv * w0.w;
            acc[m][4] += hv * w1.x; acc[m][5] += hv * w1.y;
            acc[m][6] += hv * w1.z; acc[m][7] += hv * w1.w;
        }
    }

    #pragma unroll
    for (int j = 0; j < 8; ++j) bb[j] = b2[c0 + j];

    #pragma unroll
    for (int m = 0; m < 4; ++m) {
        int gr = node0 + rg + 16 * m;
        if (gr < N_NODES) {
            v4f o0, o1;
            o0.x = acc[m][0] + bb[0]; o0.y = acc[m][1] + bb[1];
            o0.z = acc[m][2] + bb[2]; o0.w = acc[m][3] + bb[3];
            o1.x = acc[m][4] + bb[4]; o1.y = acc[m][5] + bb[5];
            o1.z = acc[m][6] + bb[6]; o1.w = acc[m][7] + bb[7];
            *reinterpret_cast<v4f*>(&z[(long)gr * C + c0])     = o0;
            *reinterpret_cast<v4f*>(&z[(long)gr * C + c0 + 4]) = o1;
        }
    }
}

// ---------- CSR build: histogram -> 2-phase exclusive scan -> bucket fill ----

__global__ __launch_bounds__(256) void zero_counts(int* __restrict__ counts) {
    int i = blockIdx.x * 256 + threadIdx.x;
    if (i < NPAD) counts[i] = 0;
}

__global__ __launch_bounds__(256) void hist_kernel(const int* __restrict__ idx,
                                                   int* __restrict__ counts) {
    int e = blockIdx.x * 256 + threadIdx.x;
    if (e < N_ROWS) atomicAdd(&counts[idx[e]], 1);
}

// Phase 1: per-block (256-wide) exclusive scan; block totals -> partials.
__global__ __launch_bounds__(256) void scan1(const int* __restrict__ counts,
                                             int* __restrict__ bases,
                                             int* __restrict__ partials) {
    __shared__ int s[256];
    int b = blockIdx.x, t = threadIdx.x, i = b * 256 + t;
    int v = (i < N_NODES) ? counts[i] : 0;
    s[t] = v; __syncthreads();
    #pragma unroll
    for (int off = 1; off < 256; off <<= 1) {
        int u = (t >= off) ? s[t - off] : 0;
        __syncthreads();
        s[t] += u;
        __syncthreads();
    }
    bases[i] = s[t] - v;                  // exclusive
    if (t == 255) partials[b] = s[t];     // inclusive total
}

// Phase 2: every block redundantly scans the 196 partials, adds its offset,
// writes the final base into cursor (csr_fill's atomic cursor array).
__global__ __launch_bounds__(256) void scan2(const int* __restrict__ bases,
                                             const int* __restrict__ partials,
                                             int* __restrict__ cursor) {
    __shared__ int s[256];
    __shared__ int ex[256];
    int b = blockIdx.x, t = threadIdx.x;
    int v = (t < NBLK) ? partials[t] : 0;
    s[t] = v; __syncthreads();
    #pragma unroll
    for (int off = 1; off < 256; off <<= 1) {
        int u = (t >= off) ? s[t - off] : 0;
        __syncthreads();
        s[t] += u;
        __syncthreads();
    }
    ex[t] = s[t] - v;
    __syncthreads();
    int offset = ex[b];
    int i = b * 256 + t;
    cursor[i] = bases[i] + offset;
}

// Fill (edge, node) pairs grouped by node.
__global__ __launch_bounds__(256) void csr_fill(const int* __restrict__ idx,
                                                int* __restrict__ cursor,
                                                int2* __restrict__ elist) {
    int e = blockIdx.x * 256 + threadIdx.x;
    if (e < N_ROWS) {
        int n = idx[e];
        int pos = atomicAdd(&cursor[n], 1);
        elist[pos] = make_int2(e, n);
    }
}

// Scatter in node-sorted order: consecutive slots share a z row -> z is read
// ~once total (L1/L2-hot) instead of 16x from L3. Each row's 512 B store is
// contiguous (full lines), non-temporal so the 410 MB stream skips L2.
__global__ __launch_bounds__(256) void scatter_kernel(
    const v4f* __restrict__ z4, const int2* __restrict__ elist,
    v4f* __restrict__ y4)
{
    long i = (long)blockIdx.x * 256 + threadIdx.x;   // over N_ROWS*32 float4s
    int slot = (int)(i >> 5);
    int c    = (int)(i & 31);
    int2 en  = elist[slot];
    v4f v = z4[(long)en.y * 32 + c];
    __builtin_nontemporal_store(v, &y4[(long)en.x * 32 + c]);
}

extern "C" void kernel_launch(void* const* d_in, const int* in_sizes, int n_in,
                              void* d_out, int out_size, void* d_ws, size_t ws_size,
                              hipStream_t stream) {
    const float* x   = (const float*)d_in[0];
    const int*   idx = (const int*)d_in[1];
    const float* W1  = (const float*)d_in[2];
    const float* b1  = (const float*)d_in[3];
    const float* W2  = (const float*)d_in[4];
    const float* b2  = (const float*)d_in[5];
    float* y = (float*)d_out;

    float* z        = (float*)d_ws;                       // 6.4M floats (25.6 MB)
    float* W1f      = z + (size_t)N_NODES * C;            // 16384 floats
    int*   counts   = (int*)(W1f + C * C);                // NPAD ints
    int*   bases    = counts + NPAD;                      // NPAD ints
    int*   cursor   = bases + NPAD;                       // NPAD ints
    int*   partials = cursor + NPAD;                      // 256 ints
    int2*  elist    = (int2*)(partials + 256);            // N_ROWS int2 (6.4 MB)

    hipLaunchKernelGGL(prep_w1f, dim3(64), dim3(256), 0, stream, W1, W1f);
    hipLaunchKernelGGL(node_kernel, dim3((N_NODES + 63) / 64), dim3(256), 0, stream,
                       x, W1f, b1, W2, b2, z);
    hipLaunchKernelGGL(zero_counts, dim3(NBLK), dim3(256), 0, stream, counts);
    hipLaunchKernelGGL(hist_kernel, dim3((N_ROWS + 255) / 256), dim3(256), 0, stream,
                       idx, counts);
    hipLaunchKernelGGL(scan1, dim3(NBLK), dim3(256), 0, stream, counts, bases, partials);
    hipLaunchKernelGGL(scan2, dim3(NBLK), dim3(256), 0, stream, bases, partials, cursor);
    hipLaunchKernelGGL(csr_fill, dim3((N_ROWS + 255) / 256), dim3(256), 0, stream,
                       idx, cursor, elist);
    hipLaunchKernelGGL(scatter_kernel, dim3((N_ROWS * 32) / 256), dim3(256), 0, stream,
                       (const v4f*)z, elist, (v4f*)y);
}